// Round 1
// baseline (1674.149 us; speedup 1.0000x reference)
//
#include <hip/hip_runtime.h>

#define SPATIAL 16384
#define BATCH 8
#define CDIM 384
#define QVDIM 768
#define PDIM 192
#define NHEADS 8
#define HC 48

typedef __attribute__((ext_vector_type(8))) short short8;
typedef __attribute__((ext_vector_type(4))) float f32x4;
typedef __attribute__((ext_vector_type(4))) int i32x4;

__device__ __forceinline__ unsigned short f2bf(float f) {
  union { float f; unsigned u; } v; v.f = f;
  unsigned r = v.u + 0x7fffu + ((v.u >> 16) & 1u);
  return (unsigned short)(r >> 16);
}
__device__ __forceinline__ float bf2f(unsigned short h) {
  union { unsigned u; float f; } v; v.u = ((unsigned)h) << 16;
  return v.f;
}

// ---------------- weight fp32 -> bf16 ----------------
__global__ void k_w2bf(const float* __restrict__ in, unsigned short* __restrict__ out, int n) {
  int i = blockIdx.x * 256 + threadIdx.x;
  if (i < n) out[i] = f2bf(in[i]);
}

// ---------------- transpose fp32 [B][C][S] -> bf16 [B][S][C] ----------------
__global__ void k_transpose(const float* __restrict__ in, unsigned short* __restrict__ out, int C) {
  __shared__ float tile[32][33];
  int bid = blockIdx.x;
  int st = bid % (SPATIAL / 32); bid /= (SPATIAL / 32);
  int ct = bid % (C / 32);  int b = bid / (C / 32);
  int tx = threadIdx.x & 31;
  int ty = threadIdx.x >> 5;
  const float* ip = in + ((size_t)b * C + (size_t)ct * 32) * SPATIAL + (size_t)st * 32;
#pragma unroll
  for (int i = 0; i < 4; i++) {
    int r = ty + i * 8;
    tile[r][tx] = ip[(size_t)r * SPATIAL + tx];
  }
  __syncthreads();
  unsigned short* op = out + ((size_t)b * SPATIAL + (size_t)st * 32) * C + (size_t)ct * 32;
#pragma unroll
  for (int i = 0; i < 4; i++) {
    int r = ty + i * 8;
    op[(size_t)r * C + tx] = f2bf(tile[tx][r]);
  }
}

// ---------------- GEMM: C[b][M][S] = A[b? ][M][K] @ B[b][S][K]^T ----------------
// A bf16 row-major [M][K] (batch stride strideA elements), B bf16 [S][K] per batch.
// 128x128 tile, 4 waves (2x2), each wave 64x64 = 4x4 frags of 16x16x32 MFMA.
template<bool OUT_BF16>
__global__ __launch_bounds__(256)
void k_gemm(const unsigned short* __restrict__ A, const unsigned short* __restrict__ B,
            void* __restrict__ Cv, int M, int K, long strideA)
{
  int bid = blockIdx.x;
  int nb = bid % (SPATIAL / 128); bid /= (SPATIAL / 128);
  int mb = bid % (M / 128); int b = bid / (M / 128);

  const unsigned short* Ab = A + (size_t)b * strideA + (size_t)mb * 128 * K;
  const unsigned short* Bb = B + ((size_t)b * SPATIAL + (size_t)nb * 128) * K;

  __shared__ unsigned short lA[128 * 32];
  __shared__ unsigned short lB[128 * 32];

  int t = threadIdx.x;
  int lane = t & 63;
  int wv = t >> 6;
  int wm = (wv >> 1) * 64, wn = (wv & 1) * 64;
  int lr = lane & 15, lg = lane >> 4;

  f32x4 acc[4][4];
#pragma unroll
  for (int i = 0; i < 4; i++)
#pragma unroll
    for (int j = 0; j < 4; j++)
      acc[i][j] = (f32x4){0.f, 0.f, 0.f, 0.f};

  int r0 = t >> 2, kc = t & 3;
  int r1 = r0 + 64;

  for (int k0 = 0; k0 < K; k0 += 32) {
    __syncthreads();
    i32x4 va0 = *(const i32x4*)(Ab + (size_t)r0 * K + k0 + kc * 8);
    i32x4 vb0 = *(const i32x4*)(Bb + (size_t)r0 * K + k0 + kc * 8);
    i32x4 va1 = *(const i32x4*)(Ab + (size_t)r1 * K + k0 + kc * 8);
    i32x4 vb1 = *(const i32x4*)(Bb + (size_t)r1 * K + k0 + kc * 8);
    *(i32x4*)(&lA[r0 * 32 + (kc ^ (r0 & 3)) * 8]) = va0;
    *(i32x4*)(&lB[r0 * 32 + (kc ^ (r0 & 3)) * 8]) = vb0;
    *(i32x4*)(&lA[r1 * 32 + (kc ^ (r1 & 3)) * 8]) = va1;
    *(i32x4*)(&lB[r1 * 32 + (kc ^ (r1 & 3)) * 8]) = vb1;
    __syncthreads();

    short8 af[4], bfr[4];
#pragma unroll
    for (int mi = 0; mi < 4; mi++) {
      int r = wm + mi * 16 + lr;
      af[mi] = *(const short8*)(&lA[r * 32 + ((lg ^ (r & 3)) * 8)]);
    }
#pragma unroll
    for (int ni = 0; ni < 4; ni++) {
      int r = wn + ni * 16 + lr;
      bfr[ni] = *(const short8*)(&lB[r * 32 + ((lg ^ (r & 3)) * 8)]);
    }
#pragma unroll
    for (int mi = 0; mi < 4; mi++)
#pragma unroll
      for (int ni = 0; ni < 4; ni++)
        acc[mi][ni] = __builtin_amdgcn_mfma_f32_16x16x32_bf16(af[mi], bfr[ni], acc[mi][ni], 0, 0, 0);
  }

  size_t rbase = (size_t)mb * 128 + wm + lg * 4;
  size_t cbase = (size_t)nb * 128 + wn + lr;
  if (OUT_BF16) {
    unsigned short* C = (unsigned short*)Cv + (size_t)b * M * SPATIAL;
#pragma unroll
    for (int mi = 0; mi < 4; mi++)
#pragma unroll
      for (int ni = 0; ni < 4; ni++) {
        size_t r = rbase + mi * 16;
        size_t c = cbase + ni * 16;
#pragma unroll
        for (int j = 0; j < 4; j++)
          C[(r + j) * SPATIAL + c] = f2bf(acc[mi][ni][j]);
      }
  } else {
    float* C = (float*)Cv + (size_t)b * M * SPATIAL;
#pragma unroll
    for (int mi = 0; mi < 4; mi++)
#pragma unroll
      for (int ni = 0; ni < 4; ni++) {
        size_t r = rbase + mi * 16;
        size_t c = cbase + ni * 16;
#pragma unroll
        for (int j = 0; j < 4; j++)
          C[(r + j) * SPATIAL + c] = acc[mi][ni][j];
      }
  }
}

// ---------------- depthwise 3x3, SAME, bf16 in/out, optional ||.||^2 atomics ----------------
template<bool NORM>
__global__ void k_dwconv(const unsigned short* __restrict__ in, const float* __restrict__ wdw,
                         unsigned short* __restrict__ out, float* __restrict__ norm2,
                         int C, int in_cstride, int chan_off)
{
  int bid = blockIdx.x;
  int st = bid % (SPATIAL / 256); bid /= (SPATIAL / 256);
  int c = bid % C; int b = bid / C;
  const unsigned short* ip = in + ((size_t)b * in_cstride + chan_off + c) * SPATIAL;
  const float* wp = wdw + (size_t)(chan_off + c) * 9;
  float w[9];
#pragma unroll
  for (int i = 0; i < 9; i++) w[i] = wp[i];
  int s = st * 256 + threadIdx.x;
  int y = s >> 7, x = s & 127;
  float acc = 0.f;
#pragma unroll
  for (int dy = -1; dy <= 1; dy++)
#pragma unroll
    for (int dx = -1; dx <= 1; dx++) {
      int yy = y + dy, xx = x + dx;
      if ((unsigned)yy < 128u && (unsigned)xx < 128u)
        acc += w[(dy + 1) * 3 + (dx + 1)] * bf2f(ip[yy * 128 + xx]);
    }
  unsigned short ob = f2bf(acc);
  out[((size_t)b * C + c) * SPATIAL + s] = ob;
  if (NORM) {
    float ov = bf2f(ob);
    float sq = ov * ov;
#pragma unroll
    for (int off = 32; off > 0; off >>= 1) sq += __shfl_down(sq, off, 64);
    __shared__ float red[4];
    if ((threadIdx.x & 63) == 0) red[threadIdx.x >> 6] = sq;
    __syncthreads();
    if (threadIdx.x == 0)
      atomicAdd(&norm2[(size_t)b * C + c], red[0] + red[1] + red[2] + red[3]);
  }
}

// ---------------- depthwise 3x3 on v-half of qv, output TRANSPOSED vT [B][S][CDIM] bf16 ----------------
__global__ void k_dwconv_t(const unsigned short* __restrict__ qv, const float* __restrict__ wdw,
                           unsigned short* __restrict__ vT)
{
  __shared__ float tile[64][33];  // [x-local][c-local]
  int bid = blockIdx.x;
  int xh = bid & 1; bid >>= 1;
  int y = bid & 127; bid >>= 7;
  int ct = bid % 12; int b = bid / 12;
  int x0 = xh * 64;
  int tx = threadIdx.x & 63;
  int ty = threadIdx.x >> 6;
  int x = x0 + tx;
  for (int ci = ty; ci < 32; ci += 4) {
    int c = CDIM + ct * 32 + ci;
    const unsigned short* ip = qv + ((size_t)b * QVDIM + c) * SPATIAL;
    const float* wp = wdw + (size_t)c * 9;
    float acc = 0.f;
#pragma unroll
    for (int dy = -1; dy <= 1; dy++)
#pragma unroll
      for (int dx = -1; dx <= 1; dx++) {
        int yy = y + dy, xx = x + dx;
        if ((unsigned)yy < 128u && (unsigned)xx < 128u)
          acc += wp[(dy + 1) * 3 + (dx + 1)] * bf2f(ip[yy * 128 + xx]);
      }
    tile[tx][ci] = acc;
  }
  __syncthreads();
  int sl = threadIdx.x >> 2;
  int cc = threadIdx.x & 3;
  short8 o;
#pragma unroll
  for (int j = 0; j < 8; j++) o[j] = (short)f2bf(tile[sl][cc * 8 + j]);
  *(short8*)(vT + ((size_t)b * SPATIAL + (size_t)y * 128 + x0 + sl) * CDIM + ct * 32 + cc * 8) = o;
}

// ---------------- raw attention logits: raw[b][h][c][d] += sum_s q[c,s]*k[d,s] ----------------
__global__ __launch_bounds__(256)
void k_logits(const unsigned short* __restrict__ qd, const unsigned short* __restrict__ kd,
              float* __restrict__ raw)
{
  int bid = blockIdx.x;
  int sp = bid & 15; bid >>= 4;
  int h = bid & 7; int b = bid >> 3;
  int lane = threadIdx.x & 63, wv = threadIdx.x >> 6;
  int lr = lane & 15, lg = lane >> 4;
  const unsigned short* qp = qd + ((size_t)b * CDIM + h * HC) * SPATIAL;
  const unsigned short* kp = kd + ((size_t)b * CDIM + h * HC) * SPATIAL;
  int s0 = sp * 1024 + wv * 256;
  f32x4 acc[3][3];
#pragma unroll
  for (int i = 0; i < 3; i++)
#pragma unroll
    for (int j = 0; j < 3; j++)
      acc[i][j] = (f32x4){0.f, 0.f, 0.f, 0.f};
  for (int ks = 0; ks < 256; ks += 32) {
    int off = s0 + ks + lg * 8;
    short8 qf[3], kf[3];
#pragma unroll
    for (int i = 0; i < 3; i++) {
      qf[i] = *(const short8*)(qp + (size_t)(i * 16 + lr) * SPATIAL + off);
      kf[i] = *(const short8*)(kp + (size_t)(i * 16 + lr) * SPATIAL + off);
    }
#pragma unroll
    for (int ci = 0; ci < 3; ci++)
#pragma unroll
      for (int di = 0; di < 3; di++)
        acc[ci][di] = __builtin_amdgcn_mfma_f32_16x16x32_bf16(qf[ci], kf[di], acc[ci][di], 0, 0, 0);
  }
  float* rp = raw + ((size_t)(b * NHEADS + h)) * HC * HC;
#pragma unroll
  for (int ci = 0; ci < 3; ci++)
#pragma unroll
    for (int di = 0; di < 3; di++)
#pragma unroll
      for (int j = 0; j < 4; j++)
        atomicAdd(&rp[(ci * 16 + lg * 4 + j) * HC + di * 16 + lr], acc[ci][di][j]);
}

// ---------------- scale by norms+temperature, softmax over d ----------------
__global__ void k_softmax(const float* __restrict__ raw, const float* __restrict__ n2q,
                          const float* __restrict__ n2k, const float* __restrict__ temp,
                          float* __restrict__ attn)
{
  int h = blockIdx.x & 7, b = blockIdx.x >> 3;
  int c = threadIdx.x;
  if (c >= HC) return;
  float tp = temp[h];
  float qn = fmaxf(sqrtf(n2q[b * CDIM + h * HC + c]), 1e-12f);
  const float* rp = raw + ((size_t)(b * NHEADS + h) * HC + c) * HC;
  float vals[HC];
  float mx = -1e30f;
#pragma unroll
  for (int d = 0; d < HC; d++) {
    float kn = fmaxf(sqrtf(n2k[b * CDIM + h * HC + d]), 1e-12f);
    float v = rp[d] * tp / (qn * kn);
    vals[d] = v;
    mx = fmaxf(mx, v);
  }
  float sum = 0.f;
#pragma unroll
  for (int d = 0; d < HC; d++) { vals[d] = expf(vals[d] - mx); sum += vals[d]; }
  float inv = 1.f / sum;
  float* ap = attn + ((size_t)(b * NHEADS + h) * HC + c) * HC;
#pragma unroll
  for (int d = 0; d < HC; d++) ap[d] = vals[d] * inv;
}

// ---------------- M[b][o][h*48+d] = sum_c wproj[o][h*48+c] * attn[b][h][c][d] ----------------
__global__ void k_mbuild(const float* __restrict__ attn, const float* __restrict__ wproj,
                         unsigned short* __restrict__ Mb)
{
  int o = blockIdx.x % CDIM, b = blockIdx.x / CDIM;
  int j = threadIdx.x;           // 0..383
  int h = j / HC, d = j % HC;
  const float* wp = wproj + (size_t)o * CDIM + h * HC;
  const float* ap = attn + (size_t)(b * NHEADS + h) * HC * HC + d;
  float s = 0.f;
#pragma unroll
  for (int cp = 0; cp < HC; cp++) s += wp[cp] * ap[cp * HC];
  Mb[((size_t)b * CDIM + o) * CDIM + j] = f2bf(s);
}

// ---------------- workspace layout (bytes) ----------------
static const size_t OFF_QV   = 0;            // 201326592  qv bf16 [B][768][S]; later reused as k_dw
static const size_t OFF_KDW  = 0;            // 100663296  (alias: qv dead after dwconvs)
static const size_t OFF_XT   = 201326592;    // 100663296  xT bf16 [B][S][384]; later q_dw [B][384][S]
static const size_t OFF_QDW  = 201326592;
static const size_t OFF_DET  = 301989888;    //  50331648  deT bf16 [B][S][192]
static const size_t OFF_VT   = 301989888;    // 100663296  vT bf16 [B][S][384] (alias over dead deT)
static const size_t OFF_KPRE = 402653184;    // 100663296  k_pre bf16 [B][384][S]
static const size_t OFF_WQVB = 503316480;    //    589824
static const size_t OFF_WKB  = 503906304;    //    147456
static const size_t OFF_N2Q  = 504053760;    //     12288
static const size_t OFF_N2K  = 504066048;    //     12288
static const size_t OFF_RAW  = 504078336;    //    589824
static const size_t OFF_ATTN = 504668160;    //    589824
static const size_t OFF_MB   = 505257984;    //   2359296  -> end 507617280 (~484 MB)

extern "C" void kernel_launch(void* const* d_in, const int* in_sizes, int n_in,
                              void* d_out, int out_size, void* d_ws, size_t ws_size,
                              hipStream_t stream) {
  const float* x      = (const float*)d_in[0];
  const float* de     = (const float*)d_in[1];
  const float* w_qv   = (const float*)d_in[2];
  const float* w_qvdw = (const float*)d_in[3];
  const float* w_k    = (const float*)d_in[4];
  const float* w_kdw  = (const float*)d_in[5];
  const float* w_proj = (const float*)d_in[6];
  const float* temp   = (const float*)d_in[7];

  char* ws = (char*)d_ws;
  unsigned short* qv    = (unsigned short*)(ws + OFF_QV);
  unsigned short* kdw   = (unsigned short*)(ws + OFF_KDW);
  unsigned short* xT    = (unsigned short*)(ws + OFF_XT);
  unsigned short* qdw   = (unsigned short*)(ws + OFF_QDW);
  unsigned short* deT   = (unsigned short*)(ws + OFF_DET);
  unsigned short* vT    = (unsigned short*)(ws + OFF_VT);
  unsigned short* kpre  = (unsigned short*)(ws + OFF_KPRE);
  unsigned short* wqvb  = (unsigned short*)(ws + OFF_WQVB);
  unsigned short* wkb   = (unsigned short*)(ws + OFF_WKB);
  float* n2q  = (float*)(ws + OFF_N2Q);
  float* n2k  = (float*)(ws + OFF_N2K);
  float* raw  = (float*)(ws + OFF_RAW);
  float* attn = (float*)(ws + OFF_ATTN);
  unsigned short* Mb = (unsigned short*)(ws + OFF_MB);

  // zero the atomic accumulators (n2q + n2k + raw are contiguous)
  hipMemsetAsync(ws + OFF_N2Q, 0, 12288 + 12288 + 589824, stream);

  // weights -> bf16
  k_w2bf<<<dim3((QVDIM * CDIM + 255) / 256), dim3(256), 0, stream>>>(w_qv, wqvb, QVDIM * CDIM);
  k_w2bf<<<dim3((CDIM * PDIM + 255) / 256), dim3(256), 0, stream>>>(w_k, wkb, CDIM * PDIM);

  // transposes: x -> xT, de -> deT
  k_transpose<<<dim3(BATCH * (CDIM / 32) * (SPATIAL / 32)), dim3(256), 0, stream>>>(x, xT, CDIM);
  k_transpose<<<dim3(BATCH * (PDIM / 32) * (SPATIAL / 32)), dim3(256), 0, stream>>>(de, deT, PDIM);

  // GEMM1: qv = w_qv @ x   (M=768, K=384)
  k_gemm<true><<<dim3(BATCH * (QVDIM / 128) * (SPATIAL / 128)), dim3(256), 0, stream>>>(
      wqvb, xT, (void*)qv, QVDIM, CDIM, 0L);
  // GEMM1b: k_pre = w_k @ de (M=384, K=192)
  k_gemm<true><<<dim3(BATCH * (CDIM / 128) * (SPATIAL / 128)), dim3(256), 0, stream>>>(
      wkb, deT, (void*)kpre, CDIM, PDIM, 0L);

  // depthwise convs
  k_dwconv<true><<<dim3(BATCH * CDIM * (SPATIAL / 256)), dim3(256), 0, stream>>>(
      qv, w_qvdw, qdw, n2q, CDIM, QVDIM, 0);
  k_dwconv_t<<<dim3(BATCH * 12 * 128 * 2), dim3(256), 0, stream>>>(qv, w_qvdw, vT);
  k_dwconv<true><<<dim3(BATCH * CDIM * (SPATIAL / 256)), dim3(256), 0, stream>>>(
      kpre, w_kdw, kdw, n2k, CDIM, CDIM, 0);

  // attention logits, softmax, combined projection matrix
  k_logits<<<dim3(BATCH * NHEADS * 16), dim3(256), 0, stream>>>(qdw, kdw, raw);
  k_softmax<<<dim3(BATCH * NHEADS), dim3(64), 0, stream>>>(raw, n2q, n2k, temp, attn);
  k_mbuild<<<dim3(BATCH * CDIM), dim3(CDIM), 0, stream>>>(attn, w_proj, Mb);

  // GEMM2: out = M[b] @ v  (M=384, K=384), fp32 output
  k_gemm<false><<<dim3(BATCH * (CDIM / 128) * (SPATIAL / 128)), dim3(256), 0, stream>>>(
      Mb, vT, d_out, CDIM, CDIM, (long)(CDIM * CDIM));
}

// Round 2
// 695.797 us; speedup vs baseline: 2.4061x; 2.4061x over previous
//
#include <hip/hip_runtime.h>

#define SPATIAL 16384
#define BATCH 8
#define CDIM 384
#define QVDIM 768
#define PDIM 192
#define NHEADS 8
#define HC 48

typedef __attribute__((ext_vector_type(8))) short short8;
typedef __attribute__((ext_vector_type(4))) float f32x4;
typedef __attribute__((ext_vector_type(4))) int i32x4;

__device__ __forceinline__ unsigned short f2bf(float f) {
  union { float f; unsigned u; } v; v.f = f;
  unsigned r = v.u + 0x7fffu + ((v.u >> 16) & 1u);
  return (unsigned short)(r >> 16);
}
__device__ __forceinline__ float bf2f(unsigned short h) {
  union { unsigned u; float f; } v; v.u = ((unsigned)h) << 16;
  return v.f;
}

// async global->LDS, 16B per lane; LDS dest is wave-uniform base + lane*16
__device__ __forceinline__ void gload16(const unsigned short* g, unsigned short* lds) {
  __builtin_amdgcn_global_load_lds(
      (const __attribute__((address_space(1))) void*)g,
      (__attribute__((address_space(3))) void*)lds,
      16, 0, 0);
}

// ---------------- weight fp32 -> bf16 ----------------
__global__ void k_w2bf(const float* __restrict__ in, unsigned short* __restrict__ out, int n) {
  int i = blockIdx.x * 256 + threadIdx.x;
  if (i < n) out[i] = f2bf(in[i]);
}

// ---------------- transpose fp32 [B][C][S] -> bf16 [B][S][C], 64x64 tiles ----------------
__global__ __launch_bounds__(256)
void k_transpose(const float* __restrict__ in, unsigned short* __restrict__ out, int C) {
  __shared__ float tile[64][65];
  int bid = blockIdx.x;
  int st = bid % (SPATIAL / 64); bid /= (SPATIAL / 64);
  int ct = bid % (C / 64); int b = bid / (C / 64);
  int t = threadIdx.x;
  const float* ip = in + ((size_t)b * C + (size_t)ct * 64) * SPATIAL + (size_t)st * 64;
  int fx = t & 15, fy = t >> 4;
#pragma unroll
  for (int i = 0; i < 4; i++) {
    int r = fy + i * 16;
    f32x4 v = *(const f32x4*)(ip + (size_t)r * SPATIAL + fx * 4);
    tile[r][fx * 4 + 0] = v[0];
    tile[r][fx * 4 + 1] = v[1];
    tile[r][fx * 4 + 2] = v[2];
    tile[r][fx * 4 + 3] = v[3];
  }
  __syncthreads();
  unsigned short* op = out + ((size_t)b * SPATIAL + (size_t)st * 64) * C + (size_t)ct * 64;
  int cg = t & 7, sr = t >> 3;
#pragma unroll
  for (int i = 0; i < 2; i++) {
    int s = sr + i * 32;
    short8 o;
#pragma unroll
    for (int j = 0; j < 8; j++) o[j] = (short)f2bf(tile[cg * 8 + j][s]);
    *(short8*)(op + (size_t)s * C + cg * 8) = o;
  }
}

// ---------------- GEMM: C[b][M][S] = A[M][K] @ B[b][S][K]^T ----------------
// global_load_lds staging (linear LDS dest, source-side XOR swizzle), mb-innermost + XCD chunk swizzle.
template<bool OUT_BF16>
__global__ __launch_bounds__(256)
void k_gemm(const unsigned short* __restrict__ A, const unsigned short* __restrict__ B,
            void* __restrict__ Cv, int M, int K, long strideA)
{
  int nwg = gridDim.x;                                // always % 8 == 0 here
  int bid = (blockIdx.x & 7) * (nwg >> 3) + (blockIdx.x >> 3);
  int mt = M >> 7;
  int mb = bid % mt; bid /= mt;
  int nb = bid & 127; int b = bid >> 7;

  const unsigned short* Ab = A + (size_t)b * strideA + (size_t)mb * 128 * K;
  const unsigned short* Bb = B + ((size_t)b * SPATIAL + (size_t)nb * 128) * K;

  __shared__ unsigned short lA[4096];
  __shared__ unsigned short lB[4096];

  int t = threadIdx.x;
  int lane = t & 63;
  int w = t >> 6;
  int wm = (w >> 1) * 64, wn = (w & 1) * 64;
  int lr = lane & 15, lg = lane >> 4;

  f32x4 acc[4][4];
#pragma unroll
  for (int i = 0; i < 4; i++)
#pragma unroll
    for (int j = 0; j < 4; j++)
      acc[i][j] = (f32x4){0.f, 0.f, 0.f, 0.f};

  int r0 = t >> 2, kc = t & 3;
  int xorc = (kc ^ (r0 & 3)) * 8;                     // (r0+64)&3 == r0&3
  const unsigned short* gA0 = Ab + (size_t)r0 * K + xorc;
  const unsigned short* gA1 = Ab + (size_t)(r0 + 64) * K + xorc;
  const unsigned short* gB0 = Bb + (size_t)r0 * K + xorc;
  const unsigned short* gB1 = Bb + (size_t)(r0 + 64) * K + xorc;
  unsigned short* sA0 = &lA[w * 512];
  unsigned short* sA1 = &lA[2048 + w * 512];
  unsigned short* sB0 = &lB[w * 512];
  unsigned short* sB1 = &lB[2048 + w * 512];

  for (int k0 = 0; k0 < K; k0 += 32) {
    __syncthreads();
    gload16(gA0 + k0, sA0);
    gload16(gA1 + k0, sA1);
    gload16(gB0 + k0, sB0);
    gload16(gB1 + k0, sB1);
    __syncthreads();                                  // compiler emits vmcnt(0) drain

    short8 af[4], bfr[4];
#pragma unroll
    for (int mi = 0; mi < 4; mi++) {
      int r = wm + mi * 16 + lr;
      af[mi] = *(const short8*)(&lA[r * 32 + ((lg ^ (r & 3)) * 8)]);
    }
#pragma unroll
    for (int ni = 0; ni < 4; ni++) {
      int r = wn + ni * 16 + lr;
      bfr[ni] = *(const short8*)(&lB[r * 32 + ((lg ^ (r & 3)) * 8)]);
    }
#pragma unroll
    for (int mi = 0; mi < 4; mi++)
#pragma unroll
      for (int ni = 0; ni < 4; ni++)
        acc[mi][ni] = __builtin_amdgcn_mfma_f32_16x16x32_bf16(af[mi], bfr[ni], acc[mi][ni], 0, 0, 0);
  }

  size_t rbase = (size_t)mb * 128 + wm + lg * 4;
  size_t cbase = (size_t)nb * 128 + wn + lr;
  if (OUT_BF16) {
    unsigned short* C = (unsigned short*)Cv + (size_t)b * M * SPATIAL;
#pragma unroll
    for (int mi = 0; mi < 4; mi++)
#pragma unroll
      for (int ni = 0; ni < 4; ni++) {
        size_t r = rbase + mi * 16;
        size_t c = cbase + ni * 16;
#pragma unroll
        for (int j = 0; j < 4; j++)
          C[(r + j) * SPATIAL + c] = f2bf(acc[mi][ni][j]);
      }
  } else {
    float* C = (float*)Cv + (size_t)b * M * SPATIAL;
#pragma unroll
    for (int mi = 0; mi < 4; mi++)
#pragma unroll
      for (int ni = 0; ni < 4; ni++) {
        size_t r = rbase + mi * 16;
        size_t c = cbase + ni * 16;
#pragma unroll
        for (int j = 0; j < 4; j++)
          C[(r + j) * SPATIAL + c] = acc[mi][ni][j];
      }
  }
}

// ---------------- depthwise 3x3, vectorized: 8 x-pixels per thread ----------------
template<bool NORM>
__global__ __launch_bounds__(256)
void k_dwconv(const unsigned short* __restrict__ in, const float* __restrict__ wdw,
              unsigned short* __restrict__ out, float* __restrict__ norm2,
              int C, int in_cstride, int chan_off)
{
  int bid = blockIdx.x;
  int yt = bid & 7; bid >>= 3;                        // 8 y-tiles of 16 rows
  int c = bid % C; int b = bid / C;
  const unsigned short* ip = in + ((size_t)b * in_cstride + chan_off + c) * SPATIAL;
  const float* wp = wdw + (size_t)(chan_off + c) * 9;
  float wr[9];
#pragma unroll
  for (int i = 0; i < 9; i++) wr[i] = wp[i];

  int t = threadIdx.x;
  int ty = t >> 4, xs = (t & 15) * 8;
  int y = yt * 16 + ty;

  float acc[8];
#pragma unroll
  for (int j = 0; j < 8; j++) acc[j] = 0.f;

  auto row = [&](int yy, float wa, float wb, float wc) {
    if ((unsigned)yy >= 128u) return;
    const unsigned short* rp = ip + yy * 128 + xs;
    short8 cv = *(const short8*)rp;
    float cf[8];
#pragma unroll
    for (int j = 0; j < 8; j++) cf[j] = bf2f((unsigned short)cv[j]);
    float lf = (xs > 0) ? bf2f(rp[-1]) : 0.f;
    float rt = (xs < 120) ? bf2f(rp[8]) : 0.f;
    acc[0] += wa * lf + wb * cf[0] + wc * cf[1];
#pragma unroll
    for (int j = 1; j < 7; j++) acc[j] += wa * cf[j - 1] + wb * cf[j] + wc * cf[j + 1];
    acc[7] += wa * cf[6] + wb * cf[7] + wc * rt;
  };
  row(y - 1, wr[0], wr[1], wr[2]);
  row(y,     wr[3], wr[4], wr[5]);
  row(y + 1, wr[6], wr[7], wr[8]);

  short8 o;
  float sq = 0.f;
#pragma unroll
  for (int j = 0; j < 8; j++) {
    o[j] = (short)f2bf(acc[j]);
    if (NORM) { float v = bf2f((unsigned short)o[j]); sq += v * v; }
  }
  *(short8*)(out + ((size_t)b * C + c) * SPATIAL + y * 128 + xs) = o;

  if (NORM) {
#pragma unroll
    for (int off = 32; off > 0; off >>= 1) sq += __shfl_down(sq, off, 64);
    __shared__ float red[4];
    if ((t & 63) == 0) red[t >> 6] = sq;
    __syncthreads();
    if (t == 0)
      atomicAdd(&norm2[(size_t)b * C + c], red[0] + red[1] + red[2] + red[3]);
  }
}

// ---------------- depthwise 3x3 on v-half of qv, vectorized, transposed out vT [B][S][384] ----------------
__global__ __launch_bounds__(256)
void k_dwconv_t(const unsigned short* __restrict__ qv, const float* __restrict__ wdw,
                unsigned short* __restrict__ vT)
{
  __shared__ float tile[128][17];                     // [x][c-local]
  int bid = blockIdx.x;
  int y = bid & 127; bid >>= 7;
  int ct = bid % 24; int b = bid / 24;                // 24 tiles of 16 channels
  int t = threadIdx.x;
  int ci = t >> 4, xs = (t & 15) * 8;
  int c = CDIM + ct * 16 + ci;
  const unsigned short* ip = qv + ((size_t)b * QVDIM + c) * SPATIAL;
  const float* wp = wdw + (size_t)c * 9;
  float wr[9];
#pragma unroll
  for (int i = 0; i < 9; i++) wr[i] = wp[i];

  float acc[8];
#pragma unroll
  for (int j = 0; j < 8; j++) acc[j] = 0.f;

  auto row = [&](int yy, float wa, float wb, float wc) {
    if ((unsigned)yy >= 128u) return;
    const unsigned short* rp = ip + yy * 128 + xs;
    short8 cv = *(const short8*)rp;
    float cf[8];
#pragma unroll
    for (int j = 0; j < 8; j++) cf[j] = bf2f((unsigned short)cv[j]);
    float lf = (xs > 0) ? bf2f(rp[-1]) : 0.f;
    float rt = (xs < 120) ? bf2f(rp[8]) : 0.f;
    acc[0] += wa * lf + wb * cf[0] + wc * cf[1];
#pragma unroll
    for (int j = 1; j < 7; j++) acc[j] += wa * cf[j - 1] + wb * cf[j] + wc * cf[j + 1];
    acc[7] += wa * cf[6] + wb * cf[7] + wc * rt;
  };
  row(y - 1, wr[0], wr[1], wr[2]);
  row(y,     wr[3], wr[4], wr[5]);
  row(y + 1, wr[6], wr[7], wr[8]);

#pragma unroll
  for (int j = 0; j < 8; j++) tile[xs + j][ci] = acc[j];
  __syncthreads();

  int xw = t >> 1, cg = t & 1;
  short8 o;
#pragma unroll
  for (int j = 0; j < 8; j++) o[j] = (short)f2bf(tile[xw][cg * 8 + j]);
  *(short8*)(vT + ((size_t)b * SPATIAL + (size_t)y * 128 + xw) * CDIM + ct * 16 + cg * 8) = o;
}

// ---------------- raw attention logits: raw[b][h][c][d] += sum_s q[c,s]*k[d,s] ----------------
__global__ __launch_bounds__(256)
void k_logits(const unsigned short* __restrict__ qd, const unsigned short* __restrict__ kd,
              float* __restrict__ raw)
{
  int bid = blockIdx.x;
  int sp = bid & 15; bid >>= 4;
  int h = bid & 7; int b = bid >> 3;
  int lane = threadIdx.x & 63, wv = threadIdx.x >> 6;
  int lr = lane & 15, lg = lane >> 4;
  const unsigned short* qp = qd + ((size_t)b * CDIM + h * HC) * SPATIAL;
  const unsigned short* kp = kd + ((size_t)b * CDIM + h * HC) * SPATIAL;
  int s0 = sp * 1024 + wv * 256;
  f32x4 acc[3][3];
#pragma unroll
  for (int i = 0; i < 3; i++)
#pragma unroll
    for (int j = 0; j < 3; j++)
      acc[i][j] = (f32x4){0.f, 0.f, 0.f, 0.f};
  for (int ks = 0; ks < 256; ks += 32) {
    int off = s0 + ks + lg * 8;
    short8 qf[3], kf[3];
#pragma unroll
    for (int i = 0; i < 3; i++) {
      qf[i] = *(const short8*)(qp + (size_t)(i * 16 + lr) * SPATIAL + off);
      kf[i] = *(const short8*)(kp + (size_t)(i * 16 + lr) * SPATIAL + off);
    }
#pragma unroll
    for (int ci = 0; ci < 3; ci++)
#pragma unroll
      for (int di = 0; di < 3; di++)
        acc[ci][di] = __builtin_amdgcn_mfma_f32_16x16x32_bf16(qf[ci], kf[di], acc[ci][di], 0, 0, 0);
  }
  float* rp = raw + ((size_t)(b * NHEADS + h)) * HC * HC;
#pragma unroll
  for (int ci = 0; ci < 3; ci++)
#pragma unroll
    for (int di = 0; di < 3; di++)
#pragma unroll
      for (int j = 0; j < 4; j++)
        atomicAdd(&rp[(ci * 16 + lg * 4 + j) * HC + di * 16 + lr], acc[ci][di][j]);
}

// ---------------- scale by norms+temperature, softmax over d ----------------
__global__ void k_softmax(const float* __restrict__ raw, const float* __restrict__ n2q,
                          const float* __restrict__ n2k, const float* __restrict__ temp,
                          float* __restrict__ attn)
{
  int h = blockIdx.x & 7, b = blockIdx.x >> 3;
  int c = threadIdx.x;
  if (c >= HC) return;
  float tp = temp[h];
  float qn = fmaxf(sqrtf(n2q[b * CDIM + h * HC + c]), 1e-12f);
  const float* rp = raw + ((size_t)(b * NHEADS + h) * HC + c) * HC;
  float vals[HC];
  float mx = -1e30f;
#pragma unroll
  for (int d = 0; d < HC; d++) {
    float kn = fmaxf(sqrtf(n2k[b * CDIM + h * HC + d]), 1e-12f);
    float v = rp[d] * tp / (qn * kn);
    vals[d] = v;
    mx = fmaxf(mx, v);
  }
  float sum = 0.f;
#pragma unroll
  for (int d = 0; d < HC; d++) { vals[d] = expf(vals[d] - mx); sum += vals[d]; }
  float inv = 1.f / sum;
  float* ap = attn + ((size_t)(b * NHEADS + h) * HC + c) * HC;
#pragma unroll
  for (int d = 0; d < HC; d++) ap[d] = vals[d] * inv;
}

// ---------------- M[b][o][h*48+d] = sum_c wproj[o][h*48+c] * attn[b][h][c][d] ----------------
__global__ void k_mbuild(const float* __restrict__ attn, const float* __restrict__ wproj,
                         unsigned short* __restrict__ Mb)
{
  int o = blockIdx.x % CDIM, b = blockIdx.x / CDIM;
  int j = threadIdx.x;           // 0..383
  int h = j / HC, d = j % HC;
  const float* wp = wproj + (size_t)o * CDIM + h * HC;
  const float* ap = attn + (size_t)(b * NHEADS + h) * HC * HC + d;
  float s = 0.f;
#pragma unroll
  for (int cp = 0; cp < HC; cp++) s += wp[cp] * ap[cp * HC];
  Mb[((size_t)b * CDIM + o) * CDIM + j] = f2bf(s);
}

// ---------------- workspace layout (bytes) ----------------
static const size_t OFF_QV   = 0;            // qv bf16 [B][768][S]; later reused as k_dw
static const size_t OFF_KDW  = 0;            // alias: qv fully consumed before this is written
static const size_t OFF_XT   = 201326592;    // xT bf16 [B][S][384]; later q_dw [B][384][S]
static const size_t OFF_QDW  = 201326592;
static const size_t OFF_DET  = 301989888;    // deT bf16 [B][S][192]
static const size_t OFF_VT   = 301989888;    // vT bf16 [B][S][384] (alias over dead deT)
static const size_t OFF_KPRE = 402653184;    // k_pre bf16 [B][384][S]
static const size_t OFF_WQVB = 503316480;
static const size_t OFF_WKB  = 503906304;
static const size_t OFF_N2Q  = 504053760;
static const size_t OFF_N2K  = 504066048;
static const size_t OFF_RAW  = 504078336;
static const size_t OFF_ATTN = 504668160;
static const size_t OFF_MB   = 505257984;    // -> end ~484 MB

extern "C" void kernel_launch(void* const* d_in, const int* in_sizes, int n_in,
                              void* d_out, int out_size, void* d_ws, size_t ws_size,
                              hipStream_t stream) {
  const float* x      = (const float*)d_in[0];
  const float* de     = (const float*)d_in[1];
  const float* w_qv   = (const float*)d_in[2];
  const float* w_qvdw = (const float*)d_in[3];
  const float* w_k    = (const float*)d_in[4];
  const float* w_kdw  = (const float*)d_in[5];
  const float* w_proj = (const float*)d_in[6];
  const float* temp   = (const float*)d_in[7];

  char* ws = (char*)d_ws;
  unsigned short* qv    = (unsigned short*)(ws + OFF_QV);
  unsigned short* kdw   = (unsigned short*)(ws + OFF_KDW);
  unsigned short* xT    = (unsigned short*)(ws + OFF_XT);
  unsigned short* qdw   = (unsigned short*)(ws + OFF_QDW);
  unsigned short* deT   = (unsigned short*)(ws + OFF_DET);
  unsigned short* vT    = (unsigned short*)(ws + OFF_VT);
  unsigned short* kpre  = (unsigned short*)(ws + OFF_KPRE);
  unsigned short* wqvb  = (unsigned short*)(ws + OFF_WQVB);
  unsigned short* wkb   = (unsigned short*)(ws + OFF_WKB);
  float* n2q  = (float*)(ws + OFF_N2Q);
  float* n2k  = (float*)(ws + OFF_N2K);
  float* raw  = (float*)(ws + OFF_RAW);
  float* attn = (float*)(ws + OFF_ATTN);
  unsigned short* Mb = (unsigned short*)(ws + OFF_MB);

  hipMemsetAsync(ws + OFF_N2Q, 0, 12288 + 12288 + 589824, stream);

  k_w2bf<<<dim3((QVDIM * CDIM + 255) / 256), dim3(256), 0, stream>>>(w_qv, wqvb, QVDIM * CDIM);
  k_w2bf<<<dim3((CDIM * PDIM + 255) / 256), dim3(256), 0, stream>>>(w_k, wkb, CDIM * PDIM);

  k_transpose<<<dim3(BATCH * (CDIM / 64) * (SPATIAL / 64)), dim3(256), 0, stream>>>(x, xT, CDIM);
  k_transpose<<<dim3(BATCH * (PDIM / 64) * (SPATIAL / 64)), dim3(256), 0, stream>>>(de, deT, PDIM);

  // GEMM1: qv = w_qv @ x   (M=768, K=384); GEMM1b: k_pre = w_k @ de (M=384, K=192)
  k_gemm<true><<<dim3(BATCH * (QVDIM / 128) * (SPATIAL / 128)), dim3(256), 0, stream>>>(
      wqvb, xT, (void*)qv, QVDIM, CDIM, 0L);
  k_gemm<true><<<dim3(BATCH * (CDIM / 128) * (SPATIAL / 128)), dim3(256), 0, stream>>>(
      wkb, deT, (void*)kpre, CDIM, PDIM, 0L);

  // depthwise convs (vectorized)
  k_dwconv<true><<<dim3(BATCH * CDIM * 8), dim3(256), 0, stream>>>(
      qv, w_qvdw, qdw, n2q, CDIM, QVDIM, 0);
  k_dwconv_t<<<dim3(BATCH * 24 * 128), dim3(256), 0, stream>>>(qv, w_qvdw, vT);
  k_dwconv<true><<<dim3(BATCH * CDIM * 8), dim3(256), 0, stream>>>(
      kpre, w_kdw, kdw, n2k, CDIM, CDIM, 0);

  // attention logits, softmax, combined projection matrix
  k_logits<<<dim3(BATCH * NHEADS * 16), dim3(256), 0, stream>>>(qdw, kdw, raw);
  k_softmax<<<dim3(BATCH * NHEADS), dim3(64), 0, stream>>>(raw, n2q, n2k, temp, attn);
  k_mbuild<<<dim3(BATCH * CDIM), dim3(CDIM), 0, stream>>>(attn, w_proj, Mb);

  // GEMM2: out = M[b] @ v  (M=384, K=384), fp32 output
  k_gemm<false><<<dim3(BATCH * (CDIM / 128) * (SPATIAL / 128)), dim3(256), 0, stream>>>(
      Mb, vT, d_out, CDIM, CDIM, (long)(CDIM * CDIM));
}

// Round 3
// 691.522 us; speedup vs baseline: 2.4210x; 1.0062x over previous
//
#include <hip/hip_runtime.h>

#define SPATIAL 16384
#define BATCH 8
#define CDIM 384
#define QVDIM 768
#define PDIM 192
#define NHEADS 8
#define HC 48

typedef __attribute__((ext_vector_type(8))) short short8;
typedef __attribute__((ext_vector_type(4))) float f32x4;
typedef __attribute__((ext_vector_type(4))) int i32x4;

__device__ __forceinline__ unsigned short f2bf(float f) {
  union { float f; unsigned u; } v; v.f = f;
  unsigned r = v.u + 0x7fffu + ((v.u >> 16) & 1u);
  return (unsigned short)(r >> 16);
}
__device__ __forceinline__ float bf2f(unsigned short h) {
  union { unsigned u; float f; } v; v.u = ((unsigned)h) << 16;
  return v.f;
}

// async global->LDS, 16B per lane; LDS dest is wave-uniform base + lane*16
__device__ __forceinline__ void gload16(const unsigned short* g, unsigned short* lds) {
  __builtin_amdgcn_global_load_lds(
      (const __attribute__((address_space(1))) void*)g,
      (__attribute__((address_space(3))) void*)lds,
      16, 0, 0);
}

// ---------------- weight fp32 -> bf16 ----------------
__global__ void k_w2bf(const float* __restrict__ in, unsigned short* __restrict__ out, int n) {
  int i = blockIdx.x * 256 + threadIdx.x;
  if (i < n) out[i] = f2bf(in[i]);
}

// ---------------- transpose fp32 [B][C][S] -> bf16 [B][S][C], 64x64 tiles ----------------
__global__ __launch_bounds__(256)
void k_transpose(const float* __restrict__ in, unsigned short* __restrict__ out, int C) {
  __shared__ float tile[64][65];
  int bid = blockIdx.x;
  int st = bid % (SPATIAL / 64); bid /= (SPATIAL / 64);
  int ct = bid % (C / 64); int b = bid / (C / 64);
  int t = threadIdx.x;
  const float* ip = in + ((size_t)b * C + (size_t)ct * 64) * SPATIAL + (size_t)st * 64;
  int fx = t & 15, fy = t >> 4;
#pragma unroll
  for (int i = 0; i < 4; i++) {
    int r = fy + i * 16;
    f32x4 v = *(const f32x4*)(ip + (size_t)r * SPATIAL + fx * 4);
    tile[r][fx * 4 + 0] = v[0];
    tile[r][fx * 4 + 1] = v[1];
    tile[r][fx * 4 + 2] = v[2];
    tile[r][fx * 4 + 3] = v[3];
  }
  __syncthreads();
  unsigned short* op = out + ((size_t)b * SPATIAL + (size_t)st * 64) * C + (size_t)ct * 64;
  int cg = t & 7, sr = t >> 3;
#pragma unroll
  for (int i = 0; i < 2; i++) {
    int s = sr + i * 32;
    short8 o;
#pragma unroll
    for (int j = 0; j < 8; j++) o[j] = (short)f2bf(tile[cg * 8 + j][s]);
    *(short8*)(op + (size_t)s * C + cg * 8) = o;
  }
}

// ---------------- GEMM: C[b][M][S] = A[M][K] @ B[b][S][K]^T ----------------
// Double-buffered 2-phase pipeline (T3-min + counted vmcnt), global_load_lds staging
// with source-side XOR swizzle (r>>1)&3 (2-way = free), mb-innermost + XCD chunk swizzle.
template<bool OUT_BF16>
__global__ __launch_bounds__(256)
void k_gemm(const unsigned short* __restrict__ A, const unsigned short* __restrict__ B,
            void* __restrict__ Cv, int M, int K, long strideA)
{
  int nwg = gridDim.x;                                // always % 8 == 0 here
  int bid = (blockIdx.x & 7) * (nwg >> 3) + (blockIdx.x >> 3);
  int mt = M >> 7;
  int mb = bid % mt; bid /= mt;
  int nb = bid & 127; int b = bid >> 7;

  const unsigned short* Ab = A + (size_t)b * strideA + (size_t)mb * 128 * K;
  const unsigned short* Bb = B + ((size_t)b * SPATIAL + (size_t)nb * 128) * K;

  __shared__ unsigned short lA[2][4096];
  __shared__ unsigned short lB[2][4096];

  int t = threadIdx.x;
  int lane = t & 63;
  int w = t >> 6;
  int wm = (w >> 1) * 64, wn = (w & 1) * 64;
  int lr = lane & 15, lg = lane >> 4;

  f32x4 acc[4][4];
#pragma unroll
  for (int i = 0; i < 4; i++)
#pragma unroll
    for (int j = 0; j < 4; j++)
      acc[i][j] = (f32x4){0.f, 0.f, 0.f, 0.f};

  int r0 = t >> 2, kc = t & 3;
  int xorc = (kc ^ ((r0 >> 1) & 3)) * 8;              // (r0+64)>>1 & 3 == (r0>>1)&3
  const unsigned short* gA0 = Ab + (size_t)r0 * K + xorc;
  const unsigned short* gA1 = Ab + (size_t)(r0 + 64) * K + xorc;
  const unsigned short* gB0 = Bb + (size_t)r0 * K + xorc;
  const unsigned short* gB1 = Bb + (size_t)(r0 + 64) * K + xorc;
  int ls0 = w * 512;                                  // element offsets in each buffer
  int ls1 = 2048 + w * 512;

  int nt = K >> 5;
  // prologue: stage tile 0 into buf 0
  gload16(gA0, &lA[0][ls0]);
  gload16(gA1, &lA[0][ls1]);
  gload16(gB0, &lB[0][ls0]);
  gload16(gB1, &lB[0][ls1]);

  // fragment read column (same for all rows: wm/wn/mi*16 are multiples of 16)
  int colr = (lg ^ ((lr >> 1) & 3)) * 8;

  for (int tile = 0; tile < nt; ++tile) {
    int cur = tile & 1;
    if (tile + 1 < nt) {
      int k0 = (tile + 1) << 5;
      gload16(gA0 + k0, &lA[cur ^ 1][ls0]);
      gload16(gA1 + k0, &lA[cur ^ 1][ls1]);
      gload16(gB0 + k0, &lB[cur ^ 1][ls0]);
      gload16(gB1 + k0, &lB[cur ^ 1][ls1]);
      asm volatile("s_waitcnt vmcnt(4)" ::: "memory");
    } else {
      asm volatile("s_waitcnt vmcnt(0)" ::: "memory");
    }
    __builtin_amdgcn_s_barrier();
    __builtin_amdgcn_sched_barrier(0);

    short8 af[4], bfr[4];
#pragma unroll
    for (int mi = 0; mi < 4; mi++)
      af[mi] = *(const short8*)(&lA[cur][(wm + mi * 16 + lr) * 32 + colr]);
#pragma unroll
    for (int ni = 0; ni < 4; ni++)
      bfr[ni] = *(const short8*)(&lB[cur][(wn + ni * 16 + lr) * 32 + colr]);
#pragma unroll
    for (int mi = 0; mi < 4; mi++)
#pragma unroll
      for (int ni = 0; ni < 4; ni++)
        acc[mi][ni] = __builtin_amdgcn_mfma_f32_16x16x32_bf16(af[mi], bfr[ni], acc[mi][ni], 0, 0, 0);

    __builtin_amdgcn_sched_barrier(0);
    __builtin_amdgcn_s_barrier();
  }

  size_t rbase = (size_t)mb * 128 + wm + lg * 4;
  size_t cbase = (size_t)nb * 128 + wn + lr;
  if (OUT_BF16) {
    unsigned short* C = (unsigned short*)Cv + (size_t)b * M * SPATIAL;
#pragma unroll
    for (int mi = 0; mi < 4; mi++)
#pragma unroll
      for (int ni = 0; ni < 4; ni++) {
        size_t r = rbase + mi * 16;
        size_t c = cbase + ni * 16;
#pragma unroll
        for (int j = 0; j < 4; j++)
          C[(r + j) * SPATIAL + c] = f2bf(acc[mi][ni][j]);
      }
  } else {
    float* C = (float*)Cv + (size_t)b * M * SPATIAL;
#pragma unroll
    for (int mi = 0; mi < 4; mi++)
#pragma unroll
      for (int ni = 0; ni < 4; ni++) {
        size_t r = rbase + mi * 16;
        size_t c = cbase + ni * 16;
#pragma unroll
        for (int j = 0; j < 4; j++)
          C[(r + j) * SPATIAL + c] = acc[mi][ni][j];
      }
  }
}

// ---------------- depthwise 3x3, vectorized: 8 x-pixels per thread ----------------
template<bool NORM>
__global__ __launch_bounds__(256)
void k_dwconv(const unsigned short* __restrict__ in, const float* __restrict__ wdw,
              unsigned short* __restrict__ out, float* __restrict__ norm2,
              int C, int in_cstride, int chan_off)
{
  int bid = blockIdx.x;
  int yt = bid & 7; bid >>= 3;                        // 8 y-tiles of 16 rows
  int c = bid % C; int b = bid / C;
  const unsigned short* ip = in + ((size_t)b * in_cstride + chan_off + c) * SPATIAL;
  const float* wp = wdw + (size_t)(chan_off + c) * 9;
  float wr[9];
#pragma unroll
  for (int i = 0; i < 9; i++) wr[i] = wp[i];

  int t = threadIdx.x;
  int ty = t >> 4, xs = (t & 15) * 8;
  int y = yt * 16 + ty;

  float acc[8];
#pragma unroll
  for (int j = 0; j < 8; j++) acc[j] = 0.f;

  auto row = [&](int yy, float wa, float wb, float wc) {
    if ((unsigned)yy >= 128u) return;
    const unsigned short* rp = ip + yy * 128 + xs;
    short8 cv = *(const short8*)rp;
    float cf[8];
#pragma unroll
    for (int j = 0; j < 8; j++) cf[j] = bf2f((unsigned short)cv[j]);
    float lf = (xs > 0) ? bf2f(rp[-1]) : 0.f;
    float rt = (xs < 120) ? bf2f(rp[8]) : 0.f;
    acc[0] += wa * lf + wb * cf[0] + wc * cf[1];
#pragma unroll
    for (int j = 1; j < 7; j++) acc[j] += wa * cf[j - 1] + wb * cf[j] + wc * cf[j + 1];
    acc[7] += wa * cf[6] + wb * cf[7] + wc * rt;
  };
  row(y - 1, wr[0], wr[1], wr[2]);
  row(y,     wr[3], wr[4], wr[5]);
  row(y + 1, wr[6], wr[7], wr[8]);

  short8 o;
  float sq = 0.f;
#pragma unroll
  for (int j = 0; j < 8; j++) {
    o[j] = (short)f2bf(acc[j]);
    if (NORM) { float v = bf2f((unsigned short)o[j]); sq += v * v; }
  }
  *(short8*)(out + ((size_t)b * C + c) * SPATIAL + y * 128 + xs) = o;

  if (NORM) {
#pragma unroll
    for (int off = 32; off > 0; off >>= 1) sq += __shfl_down(sq, off, 64);
    __shared__ float red[4];
    if ((t & 63) == 0) red[t >> 6] = sq;
    __syncthreads();
    if (t == 0)
      atomicAdd(&norm2[(size_t)b * C + c], red[0] + red[1] + red[2] + red[3]);
  }
}

// ---------------- depthwise 3x3 on v-half of qv, vectorized, transposed out vT [B][S][384] ----------------
__global__ __launch_bounds__(256)
void k_dwconv_t(const unsigned short* __restrict__ qv, const float* __restrict__ wdw,
                unsigned short* __restrict__ vT)
{
  __shared__ float tile[128][17];                     // [x][c-local]
  int bid = blockIdx.x;
  int y = bid & 127; bid >>= 7;
  int ct = bid % 24; int b = bid / 24;                // 24 tiles of 16 channels
  int t = threadIdx.x;
  int ci = t >> 4, xs = (t & 15) * 8;
  int c = CDIM + ct * 16 + ci;
  const unsigned short* ip = qv + ((size_t)b * QVDIM + c) * SPATIAL;
  const float* wp = wdw + (size_t)c * 9;
  float wr[9];
#pragma unroll
  for (int i = 0; i < 9; i++) wr[i] = wp[i];

  float acc[8];
#pragma unroll
  for (int j = 0; j < 8; j++) acc[j] = 0.f;

  auto row = [&](int yy, float wa, float wb, float wc) {
    if ((unsigned)yy >= 128u) return;
    const unsigned short* rp = ip + yy * 128 + xs;
    short8 cv = *(const short8*)rp;
    float cf[8];
#pragma unroll
    for (int j = 0; j < 8; j++) cf[j] = bf2f((unsigned short)cv[j]);
    float lf = (xs > 0) ? bf2f(rp[-1]) : 0.f;
    float rt = (xs < 120) ? bf2f(rp[8]) : 0.f;
    acc[0] += wa * lf + wb * cf[0] + wc * cf[1];
#pragma unroll
    for (int j = 1; j < 7; j++) acc[j] += wa * cf[j - 1] + wb * cf[j] + wc * cf[j + 1];
    acc[7] += wa * cf[6] + wb * cf[7] + wc * rt;
  };
  row(y - 1, wr[0], wr[1], wr[2]);
  row(y,     wr[3], wr[4], wr[5]);
  row(y + 1, wr[6], wr[7], wr[8]);

#pragma unroll
  for (int j = 0; j < 8; j++) tile[xs + j][ci] = acc[j];
  __syncthreads();

  int xw = t >> 1, cg = t & 1;
  short8 o;
#pragma unroll
  for (int j = 0; j < 8; j++) o[j] = (short)f2bf(tile[xw][cg * 8 + j]);
  *(short8*)(vT + ((size_t)b * SPATIAL + (size_t)y * 128 + xw) * CDIM + ct * 16 + cg * 8) = o;
}

// ---------------- raw attention logits: raw[b][h][c][d] += sum_s q[c,s]*k[d,s] ----------------
__global__ __launch_bounds__(256)
void k_logits(const unsigned short* __restrict__ qd, const unsigned short* __restrict__ kd,
              float* __restrict__ raw)
{
  int bid = blockIdx.x;
  int sp = bid & 15; bid >>= 4;
  int h = bid & 7; int b = bid >> 3;
  int lane = threadIdx.x & 63, wv = threadIdx.x >> 6;
  int lr = lane & 15, lg = lane >> 4;
  const unsigned short* qp = qd + ((size_t)b * CDIM + h * HC) * SPATIAL;
  const unsigned short* kp = kd + ((size_t)b * CDIM + h * HC) * SPATIAL;
  int s0 = sp * 1024 + wv * 256;
  f32x4 acc[3][3];
#pragma unroll
  for (int i = 0; i < 3; i++)
#pragma unroll
    for (int j = 0; j < 3; j++)
      acc[i][j] = (f32x4){0.f, 0.f, 0.f, 0.f};
  for (int ks = 0; ks < 256; ks += 32) {
    int off = s0 + ks + lg * 8;
    short8 qf[3], kf[3];
#pragma unroll
    for (int i = 0; i < 3; i++) {
      qf[i] = *(const short8*)(qp + (size_t)(i * 16 + lr) * SPATIAL + off);
      kf[i] = *(const short8*)(kp + (size_t)(i * 16 + lr) * SPATIAL + off);
    }
#pragma unroll
    for (int ci = 0; ci < 3; ci++)
#pragma unroll
      for (int di = 0; di < 3; di++)
        acc[ci][di] = __builtin_amdgcn_mfma_f32_16x16x32_bf16(qf[ci], kf[di], acc[ci][di], 0, 0, 0);
  }
  float* rp = raw + ((size_t)(b * NHEADS + h)) * HC * HC;
#pragma unroll
  for (int ci = 0; ci < 3; ci++)
#pragma unroll
    for (int di = 0; di < 3; di++)
#pragma unroll
      for (int j = 0; j < 4; j++)
        atomicAdd(&rp[(ci * 16 + lg * 4 + j) * HC + di * 16 + lr], acc[ci][di][j]);
}

// ---------------- scale by norms+temperature, softmax over d ----------------
__global__ void k_softmax(const float* __restrict__ raw, const float* __restrict__ n2q,
                          const float* __restrict__ n2k, const float* __restrict__ temp,
                          float* __restrict__ attn)
{
  int h = blockIdx.x & 7, b = blockIdx.x >> 3;
  int c = threadIdx.x;
  if (c >= HC) return;
  float tp = temp[h];
  float qn = fmaxf(sqrtf(n2q[b * CDIM + h * HC + c]), 1e-12f);
  const float* rp = raw + ((size_t)(b * NHEADS + h) * HC + c) * HC;
  float vals[HC];
  float mx = -1e30f;
#pragma unroll
  for (int d = 0; d < HC; d++) {
    float kn = fmaxf(sqrtf(n2k[b * CDIM + h * HC + d]), 1e-12f);
    float v = rp[d] * tp / (qn * kn);
    vals[d] = v;
    mx = fmaxf(mx, v);
  }
  float sum = 0.f;
#pragma unroll
  for (int d = 0; d < HC; d++) { vals[d] = expf(vals[d] - mx); sum += vals[d]; }
  float inv = 1.f / sum;
  float* ap = attn + ((size_t)(b * NHEADS + h) * HC + c) * HC;
#pragma unroll
  for (int d = 0; d < HC; d++) ap[d] = vals[d] * inv;
}

// ---------------- M[b][o][h*48+d] = sum_c wproj[o][h*48+c] * attn[b][h][c][d] ----------------
__global__ void k_mbuild(const float* __restrict__ attn, const float* __restrict__ wproj,
                         unsigned short* __restrict__ Mb)
{
  int o = blockIdx.x % CDIM, b = blockIdx.x / CDIM;
  int j = threadIdx.x;           // 0..383
  int h = j / HC, d = j % HC;
  const float* wp = wproj + (size_t)o * CDIM + h * HC;
  const float* ap = attn + (size_t)(b * NHEADS + h) * HC * HC + d;
  float s = 0.f;
#pragma unroll
  for (int cp = 0; cp < HC; cp++) s += wp[cp] * ap[cp * HC];
  Mb[((size_t)b * CDIM + o) * CDIM + j] = f2bf(s);
}

// ---------------- workspace layout (bytes) ----------------
static const size_t OFF_QV   = 0;            // qv bf16 [B][768][S]; later reused as k_dw
static const size_t OFF_KDW  = 0;            // alias: qv fully consumed before this is written
static const size_t OFF_XT   = 201326592;    // xT bf16 [B][S][384]; later q_dw [B][384][S]
static const size_t OFF_QDW  = 201326592;
static const size_t OFF_DET  = 301989888;    // deT bf16 [B][S][192]
static const size_t OFF_VT   = 301989888;    // vT bf16 [B][S][384] (alias over dead deT)
static const size_t OFF_KPRE = 402653184;    // k_pre bf16 [B][384][S]
static const size_t OFF_WQVB = 503316480;
static const size_t OFF_WKB  = 503906304;
static const size_t OFF_N2Q  = 504053760;
static const size_t OFF_N2K  = 504066048;
static const size_t OFF_RAW  = 504078336;
static const size_t OFF_ATTN = 504668160;
static const size_t OFF_MB   = 505257984;    // -> end ~484 MB

extern "C" void kernel_launch(void* const* d_in, const int* in_sizes, int n_in,
                              void* d_out, int out_size, void* d_ws, size_t ws_size,
                              hipStream_t stream) {
  const float* x      = (const float*)d_in[0];
  const float* de     = (const float*)d_in[1];
  const float* w_qv   = (const float*)d_in[2];
  const float* w_qvdw = (const float*)d_in[3];
  const float* w_k    = (const float*)d_in[4];
  const float* w_kdw  = (const float*)d_in[5];
  const float* w_proj = (const float*)d_in[6];
  const float* temp   = (const float*)d_in[7];

  char* ws = (char*)d_ws;
  unsigned short* qv    = (unsigned short*)(ws + OFF_QV);
  unsigned short* kdw   = (unsigned short*)(ws + OFF_KDW);
  unsigned short* xT    = (unsigned short*)(ws + OFF_XT);
  unsigned short* qdw   = (unsigned short*)(ws + OFF_QDW);
  unsigned short* deT   = (unsigned short*)(ws + OFF_DET);
  unsigned short* vT    = (unsigned short*)(ws + OFF_VT);
  unsigned short* kpre  = (unsigned short*)(ws + OFF_KPRE);
  unsigned short* wqvb  = (unsigned short*)(ws + OFF_WQVB);
  unsigned short* wkb   = (unsigned short*)(ws + OFF_WKB);
  float* n2q  = (float*)(ws + OFF_N2Q);
  float* n2k  = (float*)(ws + OFF_N2K);
  float* raw  = (float*)(ws + OFF_RAW);
  float* attn = (float*)(ws + OFF_ATTN);
  unsigned short* Mb = (unsigned short*)(ws + OFF_MB);

  hipMemsetAsync(ws + OFF_N2Q, 0, 12288 + 12288 + 589824, stream);

  k_w2bf<<<dim3((QVDIM * CDIM + 255) / 256), dim3(256), 0, stream>>>(w_qv, wqvb, QVDIM * CDIM);
  k_w2bf<<<dim3((CDIM * PDIM + 255) / 256), dim3(256), 0, stream>>>(w_k, wkb, CDIM * PDIM);

  k_transpose<<<dim3(BATCH * (CDIM / 64) * (SPATIAL / 64)), dim3(256), 0, stream>>>(x, xT, CDIM);
  k_transpose<<<dim3(BATCH * (PDIM / 64) * (SPATIAL / 64)), dim3(256), 0, stream>>>(de, deT, PDIM);

  // GEMM1: qv = w_qv @ x   (M=768, K=384); GEMM1b: k_pre = w_k @ de (M=384, K=192)
  k_gemm<true><<<dim3(BATCH * (QVDIM / 128) * (SPATIAL / 128)), dim3(256), 0, stream>>>(
      wqvb, xT, (void*)qv, QVDIM, CDIM, 0L);
  k_gemm<true><<<dim3(BATCH * (CDIM / 128) * (SPATIAL / 128)), dim3(256), 0, stream>>>(
      wkb, deT, (void*)kpre, CDIM, PDIM, 0L);

  // depthwise convs (vectorized)
  k_dwconv<true><<<dim3(BATCH * CDIM * 8), dim3(256), 0, stream>>>(
      qv, w_qvdw, qdw, n2q, CDIM, QVDIM, 0);
  k_dwconv_t<<<dim3(BATCH * 24 * 128), dim3(256), 0, stream>>>(qv, w_qvdw, vT);
  k_dwconv<true><<<dim3(BATCH * CDIM * 8), dim3(256), 0, stream>>>(
      kpre, w_kdw, kdw, n2k, CDIM, CDIM, 0);

  // attention logits, softmax, combined projection matrix
  k_logits<<<dim3(BATCH * NHEADS * 16), dim3(256), 0, stream>>>(qdw, kdw, raw);
  k_softmax<<<dim3(BATCH * NHEADS), dim3(64), 0, stream>>>(raw, n2q, n2k, temp, attn);
  k_mbuild<<<dim3(BATCH * CDIM), dim3(CDIM), 0, stream>>>(attn, w_proj, Mb);

  // GEMM2: out = M[b] @ v  (M=384, K=384), fp32 output
  k_gemm<false><<<dim3(BATCH * (CDIM / 128) * (SPATIAL / 128)), dim3(256), 0, stream>>>(
      Mb, vT, d_out, CDIM, CDIM, (long)(CDIM * CDIM));
}